// Round 3
// baseline (533.371 us; speedup 1.0000x reference)
//
#include <hip/hip_runtime.h>
#include <math.h>

#define BB 4
#define NN 2048
#define CC 3
#define HH 4
#define DD 32
#define NEG_INF_F (-1000000000.0f)

// ---------------------------------------------------------------------------
// K1: Wh = h @ W  (8192x128 @ 128x128), plus src[b,h,n] = Wh.a_src, dst = Wh.a_dst
// block = 256 (2 rows x 128 cols)
// ---------------------------------------------------------------------------
__global__ __launch_bounds__(256) void k1_wh(const float* __restrict__ h,
                                             const float* __restrict__ W,
                                             const float* __restrict__ a_src,
                                             const float* __restrict__ a_dst,
                                             float* __restrict__ Wh,
                                             float* __restrict__ srcv,
                                             float* __restrict__ dstv) {
    __shared__ float hrow[2][128];
    int tid = threadIdx.x;
    int r = tid >> 7, c = tid & 127;
    int row = blockIdx.x * 2 + r;          // 0..8191
    int b = row >> 11;
    int n = row & 2047;
    hrow[r][c] = h[row * 128 + c];
    __syncthreads();
    float acc = 0.f;
#pragma unroll
    for (int k = 0; k < 128; ++k)
        acc = fmaf(hrow[r][k], W[k * 128 + c], acc);
    Wh[row * 128 + c] = acc;
    // head-wise dot with a_src/a_dst: reduce over 32 consecutive lanes (one head)
    float ps = acc * a_src[c];
    float pd = acc * a_dst[c];
#pragma unroll
    for (int m = 16; m >= 1; m >>= 1) {
        ps += __shfl_xor(ps, m);
        pd += __shfl_xor(pd, m);
    }
    if ((c & 31) == 0) {
        int hh = c >> 5;
        srcv[(b * HH + hh) * NN + n] = ps;
        dstv[(b * HH + hh) * NN + n] = pd;
    }
}

// ---------------------------------------------------------------------------
// K2: stream adj once: mask bit = (adj[b,0,i,j]+adj[b,1,i,j]+adj[b,2,i,j]) > 0
// -> 64-bit mask words; also dmax[b,h,i] = max over unmasked j of dst[b,h,j]
// block = 256 (4 waves, 1 row per wave), grid = B*N/4
// ---------------------------------------------------------------------------
__global__ __launch_bounds__(256) void k2_mask(const float* __restrict__ adj,
                                               const float* __restrict__ dstv,
                                               unsigned long long* __restrict__ maskbits,
                                               float* __restrict__ dmax) {
    __shared__ float dl[HH][NN];  // 32 KB: dst for all 4 heads of this batch
    int tid = threadIdx.x;
    int rowg0 = blockIdx.x * 4;
    int b = rowg0 >> 11;
    for (int idx = tid; idx < HH * NN; idx += 256) {
        int hh = idx >> 11, j = idx & 2047;
        dl[hh][j] = dstv[(b * HH + hh) * NN + j];
    }
    __syncthreads();
    int wave = tid >> 6, lane = tid & 63;
    int i = (rowg0 & 2047) + wave;
    const float* a0 = adj + ((long long)(b * CC + 0) * NN + i) * NN;
    const float* a1 = adj + ((long long)(b * CC + 1) * NN + i) * NN;
    const float* a2 = adj + ((long long)(b * CC + 2) * NN + i) * NN;
    float m0 = -INFINITY, m1 = -INFINITY, m2 = -INFINITY, m3 = -INFINITY;
    for (int jt = 0; jt < NN / 64; ++jt) {
        int j = jt * 64 + lane;
        float s = a0[j] + a1[j] + a2[j];
        bool bit = s > 0.f;
        unsigned long long mw = __ballot(bit);
        if (lane == 0) maskbits[((long long)b * NN + i) * 32 + jt] = mw;
        if (bit) {
            m0 = fmaxf(m0, dl[0][j]);
            m1 = fmaxf(m1, dl[1][j]);
            m2 = fmaxf(m2, dl[2][j]);
            m3 = fmaxf(m3, dl[3][j]);
        }
    }
#pragma unroll
    for (int m = 32; m >= 1; m >>= 1) {
        m0 = fmaxf(m0, __shfl_xor(m0, m));
        m1 = fmaxf(m1, __shfl_xor(m1, m));
        m2 = fmaxf(m2, __shfl_xor(m2, m));
        m3 = fmaxf(m3, __shfl_xor(m3, m));
    }
    if (lane == 0) {
        dmax[(b * HH + 0) * NN + i] = m0;
        dmax[(b * HH + 1) * NN + i] = m1;
        dmax[(b * HH + 2) * NN + i] = m2;
        dmax[(b * HH + 3) * NN + i] = m3;
    }
}

// ---------------------------------------------------------------------------
// K3: attention. grid = (B*H) * (N/64); block = 256 (4 waves x 16 rows).
// Row max is known exactly: m_i = leakyrelu(src_i + dmax_i)  (monotonicity).
// Per j-tile (64): stage Wh[j,0:32] in LDS; phase A computes p -> LDS;
// phase B: each lane accumulates a 2-row x 4-d fp32 tile.
// ---------------------------------------------------------------------------
__global__ __launch_bounds__(256) void k3_attn(const float* __restrict__ Wh,
                                               const float* __restrict__ srcv,
                                               const float* __restrict__ dstv,
                                               const float* __restrict__ dmax,
                                               const unsigned long long* __restrict__ maskbits,
                                               float* __restrict__ attn) {
    __shared__ __align__(16) float wh_lds[64 * 32];    // [j][d], 8 KB
    __shared__ __align__(16) float p_lds[4][16 * 65];  // per-wave [r][j], stride 65
    int tid = threadIdx.x;
    int wave = tid >> 6, lane = tid & 63;
    int bh = blockIdx.x >> 5;  // 32 i-tiles per (b,h)
    int it = blockIdx.x & 31;
    int b = bh >> 2, hh = bh & 3;
    int row_base = it * 64 + wave * 16;
    int rgrp = lane >> 3, dgrp = lane & 7;
    int r0 = rgrp * 2, d0 = dgrp * 4;

    // per-row constants (fully unrolled -> registers)
    float srcR[16], mR[16];
    bool amR[16];
#pragma unroll
    for (int r = 0; r < 16; ++r) {
        int row = row_base + r;
        float s = srcv[(b * HH + hh) * NN + row];
        float dm = dmax[(b * HH + hh) * NN + row];
        bool allm = !(dm > -INFINITY);  // no unmasked neighbor
        float e = s + dm;
        float lr = e > 0.f ? e : 0.2f * e;
        srcR[r] = s;
        mR[r] = allm ? 0.f : lr;
        amR[r] = allm;
    }

    float acc[2][4] = {{0.f, 0.f, 0.f, 0.f}, {0.f, 0.f, 0.f, 0.f}};
    float lsum[2] = {0.f, 0.f};
    float* pw = p_lds[wave];

    for (int jt = 0; jt < 32; ++jt) {
        int j0 = jt * 64;
        // stage Wh tile [64][32] as float4
#pragma unroll
        for (int rep = 0; rep < 2; ++rep) {
            int f4 = rep * 256 + tid;
            int j = f4 >> 3, d4 = (f4 & 7) * 4;
            *(float4*)&wh_lds[j * 32 + d4] =
                *(const float4*)&Wh[((long long)(b * NN + j0 + j) * 128) + hh * 32 + d4];
        }
        float dv = dstv[(b * HH + hh) * NN + j0 + lane];
        // phase A: p for 16 rows at this lane's j
#pragma unroll
        for (int r = 0; r < 16; ++r) {
            int row = row_base + r;
            unsigned long long mw = maskbits[((long long)b * NN + row) * 32 + jt];
            bool bit = (mw >> lane) & 1ull;
            float e = srcR[r] + dv;
            float lr = e > 0.f ? e : 0.2f * e;
            float p = amR[r] ? 1.f : (bit ? __expf(lr - mR[r]) : 0.f);
            pw[r * 65 + lane] = p;
        }
        __syncthreads();
        // phase B: rank-1 style accumulate, 2 rows x 4 d per lane
#pragma unroll 4
        for (int j = 0; j < 64; ++j) {
            const float4 w4 = *(const float4*)&wh_lds[j * 32 + d0];
            float p0 = pw[r0 * 65 + j];
            float p1 = pw[r0 * 65 + 65 + j];
            acc[0][0] = fmaf(p0, w4.x, acc[0][0]);
            acc[0][1] = fmaf(p0, w4.y, acc[0][1]);
            acc[0][2] = fmaf(p0, w4.z, acc[0][2]);
            acc[0][3] = fmaf(p0, w4.w, acc[0][3]);
            acc[1][0] = fmaf(p1, w4.x, acc[1][0]);
            acc[1][1] = fmaf(p1, w4.y, acc[1][1]);
            acc[1][2] = fmaf(p1, w4.z, acc[1][2]);
            acc[1][3] = fmaf(p1, w4.w, acc[1][3]);
            lsum[0] += p0;
            lsum[1] += p1;
        }
        __syncthreads();
    }
    // epilogue: out = acc / l
#pragma unroll
    for (int rr = 0; rr < 2; ++rr) {
        int row = row_base + r0 + rr;
        float inv = 1.f / lsum[rr];
        float4 o;
        o.x = acc[rr][0] * inv;
        o.y = acc[rr][1] * inv;
        o.z = acc[rr][2] * inv;
        o.w = acc[rr][3] * inv;
        *(float4*)&attn[((long long)(b * NN + row) * 128) + hh * 32 + d0] = o;
    }
}

// ---------------------------------------------------------------------------
// K4: out = elu(attn @ Wo + bo)
// ---------------------------------------------------------------------------
__global__ __launch_bounds__(256) void k4_out(const float* __restrict__ attn,
                                              const float* __restrict__ Wo,
                                              const float* __restrict__ bo,
                                              float* __restrict__ out) {
    __shared__ float arow[2][128];
    int tid = threadIdx.x;
    int r = tid >> 7, c = tid & 127;
    int row = blockIdx.x * 2 + r;
    arow[r][c] = attn[row * 128 + c];
    __syncthreads();
    float acc = bo[c];
#pragma unroll
    for (int k = 0; k < 128; ++k)
        acc = fmaf(arow[r][k], Wo[k * 128 + c], acc);
    out[row * 128 + c] = acc > 0.f ? acc : expm1f(acc);
}

extern "C" void kernel_launch(void* const* d_in, const int* in_sizes, int n_in,
                              void* d_out, int out_size, void* d_ws, size_t ws_size,
                              hipStream_t stream) {
    const float* h     = (const float*)d_in[0];
    const float* adj   = (const float*)d_in[1];
    const float* W     = (const float*)d_in[2];
    const float* a_src = (const float*)d_in[3];
    const float* a_dst = (const float*)d_in[4];
    const float* Wo    = (const float*)d_in[5];
    const float* bo    = (const float*)d_in[6];
    float* out = (float*)d_out;

    char* ws = (char*)d_ws;
    float* Wh   = (float*)(ws);                          // 4 MB
    float* attn = (float*)(ws + (4 << 20));              // 4 MB
    float* srcv = (float*)(ws + (8 << 20));              // 128 KB
    float* dstv = (float*)(ws + (8 << 20) + (128 << 10));
    float* dmax = (float*)(ws + (8 << 20) + (256 << 10));
    unsigned long long* maskbits =
        (unsigned long long*)(ws + (8 << 20) + (384 << 10));  // 2 MB

    k1_wh<<<dim3(BB * NN / 2), dim3(256), 0, stream>>>(h, W, a_src, a_dst, Wh, srcv, dstv);
    k2_mask<<<dim3(BB * NN / 4), dim3(256), 0, stream>>>(adj, dstv, maskbits, dmax);
    k3_attn<<<dim3(BB * HH * (NN / 64)), dim3(256), 0, stream>>>(Wh, srcv, dstv, dmax,
                                                                 maskbits, attn);
    k4_out<<<dim3(BB * NN / 2), dim3(256), 0, stream>>>(attn, Wo, bo, out);
}

// Round 4
// 447.448 us; speedup vs baseline: 1.1920x; 1.1920x over previous
//
#include <hip/hip_runtime.h>
#include <math.h>

#define BB 4
#define NN 2048
#define CC 3
#define HH 4
#define DD 32

// ---------------------------------------------------------------------------
// K1: Wh = h @ W  (8192x128 @ 128x128), plus src[b,h,n] = Wh.a_src, dst = Wh.a_dst
// ---------------------------------------------------------------------------
__global__ __launch_bounds__(256) void k1_wh(const float* __restrict__ h,
                                             const float* __restrict__ W,
                                             const float* __restrict__ a_src,
                                             const float* __restrict__ a_dst,
                                             float* __restrict__ Wh,
                                             float* __restrict__ srcv,
                                             float* __restrict__ dstv) {
    __shared__ float hrow[2][128];
    int tid = threadIdx.x;
    int r = tid >> 7, c = tid & 127;
    int row = blockIdx.x * 2 + r;          // 0..8191
    int b = row >> 11;
    int n = row & 2047;
    hrow[r][c] = h[row * 128 + c];
    __syncthreads();
    float acc = 0.f;
#pragma unroll
    for (int k = 0; k < 128; ++k)
        acc = fmaf(hrow[r][k], W[k * 128 + c], acc);
    Wh[row * 128 + c] = acc;
    float ps = acc * a_src[c];
    float pd = acc * a_dst[c];
#pragma unroll
    for (int m = 16; m >= 1; m >>= 1) {
        ps += __shfl_xor(ps, m);
        pd += __shfl_xor(pd, m);
    }
    if ((c & 31) == 0) {
        int hh = c >> 5;
        srcv[(b * HH + hh) * NN + n] = ps;
        dstv[(b * HH + hh) * NN + n] = pd;
    }
}

// ---------------------------------------------------------------------------
// K2: stream adj once: bit = sum over channels > 0 -> 64-bit mask words;
// dmax[b,h,i] = max over unmasked j of dst[b,h,j]
// ---------------------------------------------------------------------------
__global__ __launch_bounds__(256) void k2_mask(const float* __restrict__ adj,
                                               const float* __restrict__ dstv,
                                               unsigned long long* __restrict__ maskbits,
                                               float* __restrict__ dmax) {
    __shared__ float dl[HH][NN];  // 32 KB
    int tid = threadIdx.x;
    int rowg0 = blockIdx.x * 4;
    int b = rowg0 >> 11;
    for (int idx = tid; idx < HH * NN; idx += 256) {
        int hh = idx >> 11, j = idx & 2047;
        dl[hh][j] = dstv[(b * HH + hh) * NN + j];
    }
    __syncthreads();
    int wave = tid >> 6, lane = tid & 63;
    int i = (rowg0 & 2047) + wave;
    const float* a0 = adj + ((long long)(b * CC + 0) * NN + i) * NN;
    const float* a1 = adj + ((long long)(b * CC + 1) * NN + i) * NN;
    const float* a2 = adj + ((long long)(b * CC + 2) * NN + i) * NN;
    float m0 = -INFINITY, m1 = -INFINITY, m2 = -INFINITY, m3 = -INFINITY;
#pragma unroll 4
    for (int jt = 0; jt < NN / 64; ++jt) {
        int j = jt * 64 + lane;
        float s = a0[j] + a1[j] + a2[j];
        bool bit = s > 0.f;
        unsigned long long mw = __ballot(bit);
        if (lane == 0) maskbits[((long long)b * NN + i) * 32 + jt] = mw;
        float d0v = bit ? dl[0][j] : -INFINITY;
        float d1v = bit ? dl[1][j] : -INFINITY;
        float d2v = bit ? dl[2][j] : -INFINITY;
        float d3v = bit ? dl[3][j] : -INFINITY;
        m0 = fmaxf(m0, d0v);
        m1 = fmaxf(m1, d1v);
        m2 = fmaxf(m2, d2v);
        m3 = fmaxf(m3, d3v);
    }
#pragma unroll
    for (int m = 32; m >= 1; m >>= 1) {
        m0 = fmaxf(m0, __shfl_xor(m0, m));
        m1 = fmaxf(m1, __shfl_xor(m1, m));
        m2 = fmaxf(m2, __shfl_xor(m2, m));
        m3 = fmaxf(m3, __shfl_xor(m3, m));
    }
    if (lane == 0) {
        dmax[(b * HH + 0) * NN + i] = m0;
        dmax[(b * HH + 1) * NN + i] = m1;
        dmax[(b * HH + 2) * NN + i] = m2;
        dmax[(b * HH + 3) * NN + i] = m3;
    }
}

// ---------------------------------------------------------------------------
// K3: attention partials. grid = (B*H) * (N/64) * 2 j-halves = 1024 blocks.
// block = 256 (4 waves x 16 rows). Each block handles 16 of 32 j-tiles and
// writes partial (acc, lsum) to ws. Row max exact via monotonicity:
// m_i = leakyrelu(src_i + dmax_i). Wh tile double-buffered (issue-early /
// write-late), one barrier per j-tile. p_lds is wave-local (no barrier).
// ---------------------------------------------------------------------------
__global__ __launch_bounds__(256) void k3_attn(const float* __restrict__ Wh,
                                               const float* __restrict__ srcv,
                                               const float* __restrict__ dstv,
                                               const float* __restrict__ dmax,
                                               const unsigned long long* __restrict__ maskbits,
                                               float* __restrict__ part,
                                               float* __restrict__ plsum) {
    __shared__ __align__(16) float wh_lds[2][64 * 32];  // 16 KB double-buffered
    __shared__ __align__(16) float p_lds[4][16 * 65];   // per-wave, stride 65
    int tid = threadIdx.x;
    int wave = tid >> 6, lane = tid & 63;
    int blk = blockIdx.x;
    int jh = blk & 1;
    int rest = blk >> 1;
    int it = rest & 31;
    int bh = rest >> 5;
    int b = bh >> 2, hh = bh & 3;
    int row_base = it * 64 + wave * 16;
    int rgrp = lane >> 3, dgrp = lane & 7;
    int r0 = rgrp * 2, d0 = dgrp * 4;
    int jt0 = jh * 16;
    long long bhN = (long long)(b * HH + hh) * NN;
    const float* whbase = Wh + (long long)b * NN * 128 + hh * 32;

    // per-row constants
    float srcR[16], mR[16];
    bool amR[16];
#pragma unroll
    for (int r = 0; r < 16; ++r) {
        int row = row_base + r;
        float s = srcv[bhN + row];
        float dm = dmax[bhN + row];
        bool allm = !(dm > -INFINITY);
        float e = s + dm;
        float lr = e > 0.f ? e : 0.2f * e;
        srcR[r] = s;
        mR[r] = allm ? 0.f : lr;
        amR[r] = allm;
    }

    // stage indices for this thread: two float4 per j-tile
    int f4a = tid, f4b = 256 + tid;
    int ja = f4a >> 3, da = (f4a & 7) * 4;
    int jb = f4b >> 3, db = (f4b & 7) * 4;

    // prologue: stage j-tile jt0 into buf 0
    {
        int j0 = jt0 * 64;
        float4 s0 = *(const float4*)&whbase[(long long)(j0 + ja) * 128 + da];
        float4 s1 = *(const float4*)&whbase[(long long)(j0 + jb) * 128 + db];
        *(float4*)&wh_lds[0][ja * 32 + da] = s0;
        *(float4*)&wh_lds[0][jb * 32 + db] = s1;
    }
    __syncthreads();

    float acc[2][4] = {{0.f, 0.f, 0.f, 0.f}, {0.f, 0.f, 0.f, 0.f}};
    float lsum[2] = {0.f, 0.f};
    float* pw = p_lds[wave];
    float dv = dstv[bhN + jt0 * 64 + lane];

    for (int t = 0; t < 16; ++t) {
        int jt = jt0 + t;
        int cur = t & 1;
        bool hasnext = (t < 15);
        // issue next-tile loads early (hide HBM/L2 latency under compute)
        float4 n0, n1;
        float dvn = 0.f;
        if (hasnext) {
            int jn0 = (jt + 1) * 64;
            n0 = *(const float4*)&whbase[(long long)(jn0 + ja) * 128 + da];
            n1 = *(const float4*)&whbase[(long long)(jn0 + jb) * 128 + db];
            dvn = dstv[bhN + jn0 + lane];
        }
        // phase A: p for 16 rows at this lane's j (wave-local LDS, no barrier)
        const unsigned long long* mrow =
            maskbits + ((long long)b * NN + row_base) * 32 + jt;
#pragma unroll
        for (int r = 0; r < 16; ++r) {
            unsigned long long mw = mrow[r * 32];
            bool bit = (mw >> lane) & 1ull;
            float e = srcR[r] + dv;
            float lr = e > 0.f ? e : 0.2f * e;
            float p = amR[r] ? 1.f : (bit ? __expf(lr - mR[r]) : 0.f);
            pw[r * 65 + lane] = p;
        }
        // phase B: 2 rows x 4 d per lane on current buffer
        const float* whc = wh_lds[cur];
#pragma unroll 4
        for (int j = 0; j < 64; ++j) {
            const float4 w4 = *(const float4*)&whc[j * 32 + d0];
            float p0 = pw[r0 * 65 + j];
            float p1 = pw[r0 * 65 + 65 + j];
            acc[0][0] = fmaf(p0, w4.x, acc[0][0]);
            acc[0][1] = fmaf(p0, w4.y, acc[0][1]);
            acc[0][2] = fmaf(p0, w4.z, acc[0][2]);
            acc[0][3] = fmaf(p0, w4.w, acc[0][3]);
            acc[1][0] = fmaf(p1, w4.x, acc[1][0]);
            acc[1][1] = fmaf(p1, w4.y, acc[1][1]);
            acc[1][2] = fmaf(p1, w4.z, acc[1][2]);
            acc[1][3] = fmaf(p1, w4.w, acc[1][3]);
            lsum[0] += p0;
            lsum[1] += p1;
        }
        // write-late: commit next tile to the other buffer
        if (hasnext) {
            *(float4*)&wh_lds[cur ^ 1][ja * 32 + da] = n0;
            *(float4*)&wh_lds[cur ^ 1][jb * 32 + db] = n1;
            dv = dvn;
        }
        __syncthreads();
    }

    // epilogue: write partials (tile index == blockIdx.x)
#pragma unroll
    for (int rr = 0; rr < 2; ++rr) {
        int row_local = wave * 16 + r0 + rr;  // 0..63
        float4 o;
        o.x = acc[rr][0];
        o.y = acc[rr][1];
        o.z = acc[rr][2];
        o.w = acc[rr][3];
        *(float4*)&part[((long long)blk * 64 + row_local) * 32 + d0] = o;
        if (dgrp == 0) plsum[blk * 64 + row_local] = lsum[rr];
    }
}

// ---------------------------------------------------------------------------
// K3r: reduce the 2 j-half partials and normalize -> attn
// 262144 float4 outputs; 1024 blocks x 256 threads
// ---------------------------------------------------------------------------
__global__ __launch_bounds__(256) void k3_reduce(const float* __restrict__ part,
                                                 const float* __restrict__ plsum,
                                                 float* __restrict__ attn) {
    int g = blockIdx.x * 256 + threadIdx.x;  // 0..262143
    int d4 = g & 7;
    int r = (g >> 3) & 63;
    int it = (g >> 9) & 31;
    int bh = g >> 14;
    int b = bh >> 2, hh = bh & 3;
    int tile0 = (bh * 32 + it) * 2;
    const float4 p0 = *(const float4*)&part[((long long)tile0 * 64 + r) * 32 + d4 * 4];
    const float4 p1 = *(const float4*)&part[((long long)(tile0 + 1) * 64 + r) * 32 + d4 * 4];
    float l = plsum[tile0 * 64 + r] + plsum[(tile0 + 1) * 64 + r];
    float inv = 1.f / l;
    float4 o;
    o.x = (p0.x + p1.x) * inv;
    o.y = (p0.y + p1.y) * inv;
    o.z = (p0.z + p1.z) * inv;
    o.w = (p0.w + p1.w) * inv;
    int n = it * 64 + r;
    *(float4*)&attn[((long long)(b * NN + n) * 128) + hh * 32 + d4 * 4] = o;
}

// ---------------------------------------------------------------------------
// K4: out = elu(attn @ Wo + bo)
// ---------------------------------------------------------------------------
__global__ __launch_bounds__(256) void k4_out(const float* __restrict__ attn,
                                              const float* __restrict__ Wo,
                                              const float* __restrict__ bo,
                                              float* __restrict__ out) {
    __shared__ float arow[2][128];
    int tid = threadIdx.x;
    int r = tid >> 7, c = tid & 127;
    int row = blockIdx.x * 2 + r;
    arow[r][c] = attn[row * 128 + c];
    __syncthreads();
    float acc = bo[c];
#pragma unroll
    for (int k = 0; k < 128; ++k)
        acc = fmaf(arow[r][k], Wo[k * 128 + c], acc);
    out[row * 128 + c] = acc > 0.f ? acc : expm1f(acc);
}

extern "C" void kernel_launch(void* const* d_in, const int* in_sizes, int n_in,
                              void* d_out, int out_size, void* d_ws, size_t ws_size,
                              hipStream_t stream) {
    const float* h     = (const float*)d_in[0];
    const float* adj   = (const float*)d_in[1];
    const float* W     = (const float*)d_in[2];
    const float* a_src = (const float*)d_in[3];
    const float* a_dst = (const float*)d_in[4];
    const float* Wo    = (const float*)d_in[5];
    const float* bo    = (const float*)d_in[6];
    float* out = (float*)d_out;

    char* ws = (char*)d_ws;
    float* Wh   = (float*)(ws);                                 // 4 MB
    float* attn = (float*)(ws + (4 << 20));                     // 4 MB
    float* srcv = (float*)(ws + (8 << 20));                     // 128 KB
    float* dstv = (float*)(ws + (8 << 20) + (128 << 10));       // 128 KB
    float* dmax = (float*)(ws + (8 << 20) + (256 << 10));       // 128 KB
    unsigned long long* maskbits =
        (unsigned long long*)(ws + (8 << 20) + (384 << 10));    // 2 MB
    float* part  = (float*)(ws + (10 << 20) + (384 << 10));     // 8 MB
    float* plsum = (float*)(ws + (18 << 20) + (384 << 10));     // 256 KB

    k1_wh<<<dim3(BB * NN / 2), dim3(256), 0, stream>>>(h, W, a_src, a_dst, Wh, srcv, dstv);
    k2_mask<<<dim3(BB * NN / 4), dim3(256), 0, stream>>>(adj, dstv, maskbits, dmax);
    k3_attn<<<dim3(BB * HH * (NN / 64) * 2), dim3(256), 0, stream>>>(Wh, srcv, dstv, dmax,
                                                                     maskbits, part, plsum);
    k3_reduce<<<dim3(1024), dim3(256), 0, stream>>>(part, plsum, attn);
    k4_out<<<dim3(BB * NN / 2), dim3(256), 0, stream>>>(attn, Wo, bo, out);
}

// Round 5
// 390.249 us; speedup vs baseline: 1.3667x; 1.1466x over previous
//
#include <hip/hip_runtime.h>
#include <hip/hip_bf16.h>
#include <math.h>

#define BB 4
#define NN 2048
#define CC 3
#define HH 4
#define DD 32

typedef __attribute__((ext_vector_type(8))) short bf16x8;
typedef __attribute__((ext_vector_type(4))) float f32x4;

__device__ inline unsigned short f2bf(float x) {
    __hip_bfloat16 b = __float2bfloat16(x);
    return __builtin_bit_cast(unsigned short, b);
}

// ---------------------------------------------------------------------------
// K1: Wh = h @ W  (8192x128 @ 128x128) fp32, plus src/dst head-dots.
// ---------------------------------------------------------------------------
__global__ __launch_bounds__(256) void k1_wh(const float* __restrict__ h,
                                             const float* __restrict__ W,
                                             const float* __restrict__ a_src,
                                             const float* __restrict__ a_dst,
                                             float* __restrict__ Wh,
                                             float* __restrict__ srcv,
                                             float* __restrict__ dstv) {
    __shared__ float hrow[2][128];
    int tid = threadIdx.x;
    int r = tid >> 7, c = tid & 127;
    int row = blockIdx.x * 2 + r;          // 0..8191
    int b = row >> 11;
    int n = row & 2047;
    hrow[r][c] = h[row * 128 + c];
    __syncthreads();
    float acc = 0.f;
#pragma unroll
    for (int k = 0; k < 128; ++k)
        acc = fmaf(hrow[r][k], W[k * 128 + c], acc);
    Wh[row * 128 + c] = acc;
    float ps = acc * a_src[c];
    float pd = acc * a_dst[c];
#pragma unroll
    for (int m = 16; m >= 1; m >>= 1) {
        ps += __shfl_xor(ps, m);
        pd += __shfl_xor(pd, m);
    }
    if ((c & 31) == 0) {
        int hh = c >> 5;
        srcv[(b * HH + hh) * NN + n] = ps;
        dstv[(b * HH + hh) * NN + n] = pd;
    }
}

// ---------------------------------------------------------------------------
// K1t: WhT[bh][d][j] (bf16) = Wh[b][j][hh*32+d].  512 blocks x 256.
// Lane: d = dgrp*16 + (lane&15); 8 consecutive j at jc.  Reads coalesced
// per 16-lane group; 16B stores, 4 lane-groups complete each 64B line.
// ---------------------------------------------------------------------------
__global__ __launch_bounds__(256) void k1t(const float* __restrict__ Wh,
                                           unsigned short* __restrict__ WhT) {
    int tid = threadIdx.x;
    int wave = tid >> 6, lane = tid & 63;
    int blk = blockIdx.x;           // bh(16) x dgrp(2) x jb(16)
    int jb = blk & 15;
    int dgrp = (blk >> 4) & 1;
    int bh = blk >> 5;
    int b = bh >> 2, hh = bh & 3;
    int d = dgrp * 16 + (lane & 15);
    int jc = jb * 128 + wave * 32 + (lane >> 4) * 8;
    const float* src = Wh + ((long long)(b * NN + jc)) * 128 + hh * 32 + d;
    bf16x8 v;
#pragma unroll
    for (int i = 0; i < 8; ++i)
        v[i] = (short)f2bf(src[i * 128]);
    *(bf16x8*)&WhT[((long long)bh * 32 + d) * NN + jc] = v;
}

// ---------------------------------------------------------------------------
// K2: stream adj once with float4 loads: bit = (c0+c1+c2 > 0).
// 32-bit mask word per 32 j assembled via 8-lane OR-shuffle.
// dmax[b,h,i] = max over unmasked j of dst[b,h,j] (float4 LDS reads).
// ---------------------------------------------------------------------------
__global__ __launch_bounds__(256) void k2_mask(const float* __restrict__ adj,
                                               const float* __restrict__ dstv,
                                               unsigned* __restrict__ maskb32,
                                               float* __restrict__ dmax) {
    __shared__ float dl[HH][NN];  // 32 KB
    int tid = threadIdx.x;
    int rowg0 = blockIdx.x * 4;
    int b = rowg0 >> 11;
    {
        const float4* s4 = (const float4*)(dstv + (long long)b * HH * NN);
        float4* d4 = (float4*)&dl[0][0];
        for (int idx = tid; idx < HH * NN / 4; idx += 256) d4[idx] = s4[idx];
    }
    __syncthreads();
    int wave = tid >> 6, lane = tid & 63;
    int i = (rowg0 & 2047) + wave;
    const float* a0 = adj + ((long long)(b * CC + 0) * NN + i) * NN;
    const float* a1 = adj + ((long long)(b * CC + 1) * NN + i) * NN;
    const float* a2 = adj + ((long long)(b * CC + 2) * NN + i) * NN;
    float m0 = -INFINITY, m1 = -INFINITY, m2 = -INFINITY, m3 = -INFINITY;
    for (int jt = 0; jt < 8; ++jt) {
        int j4 = jt * 256 + lane * 4;
        float4 f0 = *(const float4*)&a0[j4];
        float4 f1 = *(const float4*)&a1[j4];
        float4 f2 = *(const float4*)&a2[j4];
        unsigned nib = (unsigned)(f0.x + f1.x + f2.x > 0.f) |
                       ((unsigned)(f0.y + f1.y + f2.y > 0.f) << 1) |
                       ((unsigned)(f0.z + f1.z + f2.z > 0.f) << 2) |
                       ((unsigned)(f0.w + f1.w + f2.w > 0.f) << 3);
        unsigned w = nib << (4 * (lane & 7));
        w |= __shfl_xor((int)w, 1);
        w |= __shfl_xor((int)w, 2);
        w |= __shfl_xor((int)w, 4);
        if ((lane & 7) == 0) maskb32[((long long)b * NN + i) * 64 + (j4 >> 5)] = w;
#pragma unroll
        for (int hh = 0; hh < HH; ++hh) {
            float4 dv4 = ((const float4*)&dl[hh][0])[jt * 64 + lane];
            float a = (nib & 1) ? dv4.x : -INFINITY;
            float bb2 = (nib & 2) ? dv4.y : -INFINITY;
            float cc2 = (nib & 4) ? dv4.z : -INFINITY;
            float dd2 = (nib & 8) ? dv4.w : -INFINITY;
            float mx = fmaxf(fmaxf(a, bb2), fmaxf(cc2, dd2));
            if (hh == 0) m0 = fmaxf(m0, mx);
            if (hh == 1) m1 = fmaxf(m1, mx);
            if (hh == 2) m2 = fmaxf(m2, mx);
            if (hh == 3) m3 = fmaxf(m3, mx);
        }
    }
#pragma unroll
    for (int m = 32; m >= 1; m >>= 1) {
        m0 = fmaxf(m0, __shfl_xor(m0, m));
        m1 = fmaxf(m1, __shfl_xor(m1, m));
        m2 = fmaxf(m2, __shfl_xor(m2, m));
        m3 = fmaxf(m3, __shfl_xor(m3, m));
    }
    if (lane == 0) {
        dmax[(b * HH + 0) * NN + i] = m0;
        dmax[(b * HH + 1) * NN + i] = m1;
        dmax[(b * HH + 2) * NN + i] = m2;
        dmax[(b * HH + 3) * NN + i] = m3;
    }
}

// ---------------------------------------------------------------------------
// K3: MFMA attention partials. grid = (B*H)*(N/64)*2 j-halves = 1024 blocks,
// 4 waves x 16 rows, ZERO LDS, zero barriers.
// A-frag (P): lane holds row (lane&15), k = (lane>>4)*8 + i — p computed
// in-register (exact row max via monotonicity: m = LR(src + dmax)).
// B-frag (Wh): 16B direct loads from bf16 WhT[d][j] (L2-resident).
// D: row = (lane>>4)*4 + reg, col = lane&15 (per verified gfx950 mapping).
// ---------------------------------------------------------------------------
__global__ __launch_bounds__(256) void k3_attn(const unsigned short* __restrict__ WhT,
                                               const float* __restrict__ srcv,
                                               const float* __restrict__ dstv,
                                               const float* __restrict__ dmax,
                                               const unsigned* __restrict__ maskb32,
                                               float* __restrict__ part,
                                               float* __restrict__ plsum) {
    int tid = threadIdx.x;
    int wave = tid >> 6, lane = tid & 63;
    int blk = blockIdx.x;
    int jh = blk & 1;
    int rest = blk >> 1;
    int it = rest & 31;
    int bh = rest >> 5;
    int b = bh >> 2;
    int r = lane & 15, kg = lane >> 4;
    long long bhN = (long long)bh * NN;
    int row = it * 64 + wave * 16 + r;

    float s = srcv[bhN + row];
    float dm = dmax[bhN + row];
    bool allm = !(dm > -INFINITY);
    float e0 = s + dm;
    float m = e0 > 0.f ? e0 : 0.2f * e0;
    if (allm) m = 0.f;

    const unsigned* mrow = maskb32 + ((long long)b * NN + row) * 64;
    const unsigned short* wb = WhT + (long long)bh * 32 * NN;
    const unsigned short* w0 = wb + (long long)r * NN;
    const unsigned short* w1 = wb + (long long)(16 + r) * NN;

    f32x4 acc0 = {0.f, 0.f, 0.f, 0.f};
    f32x4 acc1 = {0.f, 0.f, 0.f, 0.f};
    float psum = 0.f;

    for (int t = 0; t < 32; ++t) {
        unsigned mw = mrow[jh * 32 + t];
        int jk = jh * 1024 + t * 32 + kg * 8;
        float4 dva = *(const float4*)&dstv[bhN + jk];
        float4 dvb = *(const float4*)&dstv[bhN + jk + 4];
        float dvs[8] = {dva.x, dva.y, dva.z, dva.w, dvb.x, dvb.y, dvb.z, dvb.w};
        bf16x8 af;
#pragma unroll
        for (int i = 0; i < 8; ++i) {
            float e = s + dvs[i];
            float lr = e > 0.f ? e : 0.2f * e;
            bool bit = (mw >> (kg * 8 + i)) & 1u;
            float p = allm ? 1.f : (bit ? __expf(lr - m) : 0.f);
            psum += p;
            af[i] = (short)f2bf(p);
        }
        bf16x8 bf0 = *(const bf16x8*)&w0[jk];
        bf16x8 bf1 = *(const bf16x8*)&w1[jk];
        acc0 = __builtin_amdgcn_mfma_f32_16x16x32_bf16(af, bf0, acc0, 0, 0, 0);
        acc1 = __builtin_amdgcn_mfma_f32_16x16x32_bf16(af, bf1, acc1, 0, 0, 0);
    }

    // row-sum of p: lanes l, l+16, l+32, l+48 share a row
    psum += __shfl_xor(psum, 16);
    psum += __shfl_xor(psum, 32);

    long long pbase = (long long)blk * 64 + wave * 16;
#pragma unroll
    for (int reg = 0; reg < 4; ++reg) {
        int rl = kg * 4 + reg;
        part[(pbase + rl) * 32 + r] = acc0[reg];
        part[(pbase + rl) * 32 + 16 + r] = acc1[reg];
    }
    if (kg == 0) plsum[pbase + r] = psum;
}

// ---------------------------------------------------------------------------
// K3r: reduce the 2 j-half partials and normalize -> attn (fp32)
// ---------------------------------------------------------------------------
__global__ __launch_bounds__(256) void k3_reduce(const float* __restrict__ part,
                                                 const float* __restrict__ plsum,
                                                 float* __restrict__ attn) {
    int g = blockIdx.x * 256 + threadIdx.x;  // 0..262143
    int d4 = g & 7;
    int r = (g >> 3) & 63;
    int it = (g >> 9) & 31;
    int bh = g >> 14;
    int b = bh >> 2, hh = bh & 3;
    int tile0 = (bh * 32 + it) * 2;
    const float4 p0 = *(const float4*)&part[((long long)tile0 * 64 + r) * 32 + d4 * 4];
    const float4 p1 = *(const float4*)&part[((long long)(tile0 + 1) * 64 + r) * 32 + d4 * 4];
    float l = plsum[tile0 * 64 + r] + plsum[(tile0 + 1) * 64 + r];
    float inv = 1.f / l;
    float4 o;
    o.x = (p0.x + p1.x) * inv;
    o.y = (p0.y + p1.y) * inv;
    o.z = (p0.z + p1.z) * inv;
    o.w = (p0.w + p1.w) * inv;
    int n = it * 64 + r;
    *(float4*)&attn[((long long)(b * NN + n) * 128) + hh * 32 + d4 * 4] = o;
}

// ---------------------------------------------------------------------------
// K4: out = elu(attn @ Wo + bo)
// ---------------------------------------------------------------------------
__global__ __launch_bounds__(256) void k4_out(const float* __restrict__ attn,
                                              const float* __restrict__ Wo,
                                              const float* __restrict__ bo,
                                              float* __restrict__ out) {
    __shared__ float arow[2][128];
    int tid = threadIdx.x;
    int r = tid >> 7, c = tid & 127;
    int row = blockIdx.x * 2 + r;
    arow[r][c] = attn[row * 128 + c];
    __syncthreads();
    float acc = bo[c];
#pragma unroll
    for (int k = 0; k < 128; ++k)
        acc = fmaf(arow[r][k], Wo[k * 128 + c], acc);
    out[row * 128 + c] = acc > 0.f ? acc : expm1f(acc);
}

extern "C" void kernel_launch(void* const* d_in, const int* in_sizes, int n_in,
                              void* d_out, int out_size, void* d_ws, size_t ws_size,
                              hipStream_t stream) {
    const float* h     = (const float*)d_in[0];
    const float* adj   = (const float*)d_in[1];
    const float* W     = (const float*)d_in[2];
    const float* a_src = (const float*)d_in[3];
    const float* a_dst = (const float*)d_in[4];
    const float* Wo    = (const float*)d_in[5];
    const float* bo    = (const float*)d_in[6];
    float* out = (float*)d_out;

    char* ws = (char*)d_ws;
    float* Wh    = (float*)(ws);                               // 4 MB
    float* attn  = (float*)(ws + (4 << 20));                   // 4 MB
    float* srcv  = (float*)(ws + (8 << 20));                   // 128 KB
    float* dstv  = (float*)(ws + (8 << 20) + (128 << 10));     // 128 KB
    float* dmax  = (float*)(ws + (8 << 20) + (256 << 10));     // 128 KB
    unsigned* maskb32 = (unsigned*)(ws + (8 << 20) + (384 << 10));  // 2 MB
    float* part  = (float*)(ws + (10 << 20) + (384 << 10));    // 8 MB
    float* plsum = (float*)(ws + (18 << 20) + (384 << 10));    // 256 KB
    unsigned short* WhT = (unsigned short*)(ws + (18 << 20) + (640 << 10));  // 2 MB

    k1_wh<<<dim3(BB * NN / 2), dim3(256), 0, stream>>>(h, W, a_src, a_dst, Wh, srcv, dstv);
    k1t<<<dim3(512), dim3(256), 0, stream>>>(Wh, WhT);
    k2_mask<<<dim3(BB * NN / 4), dim3(256), 0, stream>>>(adj, dstv, maskb32, dmax);
    k3_attn<<<dim3(BB * HH * (NN / 64) * 2), dim3(256), 0, stream>>>(WhT, srcv, dstv, dmax,
                                                                     maskb32, part, plsum);
    k3_reduce<<<dim3(1024), dim3(256), 0, stream>>>(part, plsum, attn);
    k4_out<<<dim3(BB * NN / 2), dim3(256), 0, stream>>>(attn, Wo, bo, out);
}